// Round 6
// baseline (477.234 us; speedup 1.0000x reference)
//
#include <hip/hip_runtime.h>

#define HH 512
#define WW 512
#define BB 4
#define SH 64
#define SW 64
#define NPRE 128
#define LAMV 0.24f
#define EPSV 1e-8f

typedef unsigned long long u64;

// ---------------- prep: cv / ch edge weights (unchanged, verified) ----------------
__global__ __launch_bounds__(256) void prep_kernel(
    const float* __restrict__ image, const float* __restrict__ ybic,
    const float* __restrict__ logk,
    float* __restrict__ cv, float* __restrict__ ch)
{
    int idx = blockIdx.x * 256 + threadIdx.x;
    if (idx >= BB * HH * WW) return;
    int x = idx % WW;
    int y = (idx / WW) % HH;
    int b = idx / (WW * HH);

    float K = expf(logk[0]);
    float invK2 = 1.0f / (K * K);

    const float* img = image + (size_t)b * 3 * HH * WW;
    const float* yb  = ybic  + (size_t)b * HH * WW;

    float f0 = img[y * WW + x];
    float f1 = img[HH * WW + y * WW + x];
    float f2 = img[2 * HH * WW + y * WW + x];
    float f3 = yb[y * WW + x];

    if (y < HH - 1) {
        float s = fabsf(img[(y + 1) * WW + x] - f0)
                + fabsf(img[HH * WW + (y + 1) * WW + x] - f1)
                + fabsf(img[2 * HH * WW + (y + 1) * WW + x] - f2)
                + fabsf(yb[(y + 1) * WW + x] - f3);
        s *= 0.25f;
        cv[(size_t)b * (HH - 1) * WW + y * WW + x] = 1.0f / (1.0f + s * s * invK2);
    }
    if (x < WW - 1) {
        float s = fabsf(img[y * WW + x + 1] - f0)
                + fabsf(img[HH * WW + y * WW + x + 1] - f1)
                + fabsf(img[2 * HH * WW + y * WW + x + 1] - f2)
                + fabsf(yb[y * WW + x + 1] - f3);
        s *= 0.25f;
        ch[(size_t)b * HH * (WW - 1) + y * (WW - 1) + x] = 1.0f / (1.0f + s * s * invK2);
    }
}

// 8B relaxed agent-scope data words (2 floats, untagged); 4B flags polled once per dep.
__device__ __forceinline__ void st8(u64* p, float a, float b) {
    u64 v = __builtin_bit_cast(u64, make_float2(a, b));
    __hip_atomic_store(p, v, __ATOMIC_RELAXED, __HIP_MEMORY_SCOPE_AGENT);
}
__device__ __forceinline__ float2 ld8(u64* p) {
    u64 v = __hip_atomic_load(p, __ATOMIC_RELAXED, __HIP_MEMORY_SCOPE_AGENT);
    return __builtin_bit_cast(float2, v);
}
__device__ __forceinline__ void gwait(int* f, int gen) {
    while (__hip_atomic_load(f, __ATOMIC_RELAXED, __HIP_MEMORY_SCOPE_AGENT) != gen) {}
}
__device__ __forceinline__ void lwait(int* f, int gen) {
    while (__hip_atomic_load(f, __ATOMIC_RELAXED, __HIP_MEMORY_SCOPE_WORKGROUP) != gen) {}
}

// ---------------- persistent wave-dataflow kernel: NO barriers in the loop ----------------
// Grid (8,8,4) x 256 thr; thread = 4x4 px; wave = 16-row band. Horizontal halos via
// shuffles; wave-to-wave via LDS rows + LDS flags; WG-to-WG via IF$ atomics + per-(wave,dir)
// flags written after a wave-local vmcnt(0) drain. Exact-gen polls; parity double buffers.
__global__ __launch_bounds__(256) void persist_kernel(
    const float* __restrict__ ybic, float* __restrict__ out_img,
    const float* __restrict__ cv, const float* __restrict__ ch,
    const float* __restrict__ src, const float* __restrict__ mask,
    int* __restrict__ flg, u64* __restrict__ dat)
{
    const int b = blockIdx.z, tileY = blockIdx.y, tileX = blockIdx.x;
    const int tid = threadIdx.x;
    const int tx = tid & 15, ty = tid >> 4;
    const int w  = tid >> 6;              // wave index 0..3 (ty>>2)
    const int lane = tid & 63;
    const int y0 = tileY * 64 + ty * 4, x0 = tileX * 64 + tx * 4;

    // flag arrays (ints): HFT[2][4][8][8], HFB[2][4][8][8], VFL[2][4][8][8][4], VFR[...]
    int* HFT = flg;
    int* HFB = flg + 512;
    int* VFL = flg + 1024;
    int* VFR = flg + 3072;
    // data arrays (u64): HDT[2][4][8][8][32], HDB same; VDL[2][4][8][8][4][8], VDR same
    u64* HDT = dat;
    u64* HDB = dat + 16384;
    u64* VDL = dat + 32768;
    u64* VDR = dat + 49152;

    const int hIdx = (b * 8 + tileY) * 8 + tileX;
    const int vIdx = hIdx * 4 + w;

    // ---- load state into registers (identical math to verified rounds) ----
    float I[4][4];
    #pragma unroll
    for (int r = 0; r < 4; ++r) {
        float4 t = *(const float4*)(ybic + ((size_t)b * HH + y0 + r) * WW + x0);
        I[r][0] = t.x; I[r][1] = t.y; I[r][2] = t.z; I[r][3] = t.w;
    }
    float cvaL[5][4];
    #pragma unroll
    for (int i = 0; i < 5; ++i) {
        int y = y0 - 1 + i;
        if (y >= 0 && y < HH - 1) {
            float4 t = *(const float4*)(cv + ((size_t)b * (HH - 1) + y) * WW + x0);
            cvaL[i][0] = t.x * LAMV; cvaL[i][1] = t.y * LAMV;
            cvaL[i][2] = t.z * LAMV; cvaL[i][3] = t.w * LAMV;
        } else {
            #pragma unroll
            for (int c = 0; c < 4; ++c) cvaL[i][c] = 0.0f;
        }
    }
    float chaL[4][5];
    #pragma unroll
    for (int r = 0; r < 4; ++r) {
        const float* row = ch + ((size_t)b * HH + y0 + r) * (WW - 1);
        #pragma unroll
        for (int j = 0; j < 5; ++j) {
            int x = x0 - 1 + j;
            chaL[r][j] = ((unsigned)x <= (unsigned)(WW - 2)) ? row[x] * LAMV : 0.0f;
        }
    }
    const size_t sidx = ((size_t)b * SH + (y0 >> 3)) * SW + (x0 >> 3);
    const float sv = src[sidx];
    const bool useR = (mask[sidx] >= 0.5f);

    // LDS wave-to-wave rows, parity double-buffered + per-wave flags
    __shared__ float rowTop[2][4][64];
    __shared__ float rowBot[2][4][64];
    __shared__ int   wflag[2][4];
    if (tid < 8) wflag[tid >> 2][tid & 3] = 0;
    __syncthreads();   // one-time init barrier only

    const bool pubGT = (ty == 0)  && (tileY > 0);
    const bool pubGB = (ty == 15) && (tileY < 7);
    const bool pubGL = (tx == 0)  && (tileX > 0);
    const bool pubGR = (tx == 15) && (tileX < 7);
    const int tyq = ty & 3;

    #pragma unroll 1
    for (int k = 0; k < NPRE; ++k) {
        const int p = k & 1;
        const int gen = k + 1;
        const int hOff = p * 256 + hIdx;
        const int vOff = p * 1024 + vIdx;

        // ---- global publishes (fire-and-forget data) ----
        if (pubGT) {
            u64* e = HDT + (size_t)hOff * 32 + tx * 2;
            st8(e + 0, I[0][0], I[0][1]); st8(e + 1, I[0][2], I[0][3]);
        }
        if (pubGB) {
            u64* e = HDB + (size_t)hOff * 32 + tx * 2;
            st8(e + 0, I[3][0], I[3][1]); st8(e + 1, I[3][2], I[3][3]);
        }
        if (pubGL) {
            u64* e = VDL + (size_t)vOff * 8 + tyq * 2;
            st8(e + 0, I[0][0], I[1][0]); st8(e + 1, I[2][0], I[3][0]);
        }
        if (pubGR) {
            u64* e = VDR + (size_t)vOff * 8 + tyq * 2;
            st8(e + 0, I[0][3], I[1][3]); st8(e + 1, I[2][3], I[3][3]);
        }
        // wave-local drain: data at coherence point before flags issue
        asm volatile("s_waitcnt vmcnt(0)" ::: "memory");
        if (tid == 0 && tileY > 0)
            __hip_atomic_store(&HFT[hOff], gen, __ATOMIC_RELAXED, __HIP_MEMORY_SCOPE_AGENT);
        if (tid == 255 && tileY < 7)
            __hip_atomic_store(&HFB[hOff], gen, __ATOMIC_RELAXED, __HIP_MEMORY_SCOPE_AGENT);
        if (lane == 0 && tileX > 0)
            __hip_atomic_store(&VFL[vOff], gen, __ATOMIC_RELAXED, __HIP_MEMORY_SCOPE_AGENT);
        if (lane == 63 && tileX < 7)
            __hip_atomic_store(&VFR[vOff], gen, __ATOMIC_RELAXED, __HIP_MEMORY_SCOPE_AGENT);

        // ---- LDS publishes (wave-to-wave vertical) ----
        if (tyq == 0 && w > 0)
            *(float4*)&rowTop[p][w][tx * 4] = make_float4(I[0][0], I[0][1], I[0][2], I[0][3]);
        if (tyq == 3 && w < 3)
            *(float4*)&rowBot[p][w][tx * 4] = make_float4(I[3][0], I[3][1], I[3][2], I[3][3]);
        asm volatile("s_waitcnt lgkmcnt(0)" ::: "memory");
        if (lane == 0)
            __hip_atomic_store(&wflag[p][w], gen, __ATOMIC_RELAXED, __HIP_MEMORY_SCOPE_WORKGROUP);

        // ---- intra-wave shuffles (iteration-k values, register-only) ----
        float upS[4], dnS[4], lfS[4], rgS[4];
        #pragma unroll
        for (int c = 0; c < 4; ++c) {
            upS[c] = __shfl_up(I[3][c], 16);
            dnS[c] = __shfl_down(I[0][c], 16);
        }
        #pragma unroll
        for (int r = 0; r < 4; ++r) {
            lfS[r] = __shfl_up(I[r][3], 1);
            rgS[r] = __shfl_down(I[r][0], 1);
        }

        // ---- resolve halos: shuffles -> LDS polls -> global polls ----
        float up[4], dn[4], lf[4], rg[4];

        if (tyq != 0) {
            #pragma unroll
            for (int c = 0; c < 4; ++c) up[c] = upS[c];
        } else if (w > 0) {
            lwait(&wflag[p][w - 1], gen);
            asm volatile("" ::: "memory");
            float4 t = *(float4*)&rowBot[p][w - 1][tx * 4];
            up[0] = t.x; up[1] = t.y; up[2] = t.z; up[3] = t.w;
        } else if (tileY > 0) {
            gwait(&HFB[hOff - 8], gen);
            asm volatile("" ::: "memory");
            u64* e = HDB + (size_t)(hOff - 8) * 32 + tx * 2;
            float2 a = ld8(e), c2 = ld8(e + 1);
            up[0] = a.x; up[1] = a.y; up[2] = c2.x; up[3] = c2.y;
        } else { up[0] = up[1] = up[2] = up[3] = 0.0f; }

        if (tyq != 3) {
            #pragma unroll
            for (int c = 0; c < 4; ++c) dn[c] = dnS[c];
        } else if (w < 3) {
            lwait(&wflag[p][w + 1], gen);
            asm volatile("" ::: "memory");
            float4 t = *(float4*)&rowTop[p][w + 1][tx * 4];
            dn[0] = t.x; dn[1] = t.y; dn[2] = t.z; dn[3] = t.w;
        } else if (tileY < 7) {
            gwait(&HFT[hOff + 8], gen);
            asm volatile("" ::: "memory");
            u64* e = HDT + (size_t)(hOff + 8) * 32 + tx * 2;
            float2 a = ld8(e), c2 = ld8(e + 1);
            dn[0] = a.x; dn[1] = a.y; dn[2] = c2.x; dn[3] = c2.y;
        } else { dn[0] = dn[1] = dn[2] = dn[3] = 0.0f; }

        if (tx > 0) {
            #pragma unroll
            for (int r = 0; r < 4; ++r) lf[r] = lfS[r];
        } else if (tileX > 0) {
            gwait(&VFR[vOff - 4], gen);
            asm volatile("" ::: "memory");
            u64* e = VDR + (size_t)(vOff - 4) * 8 + tyq * 2;
            float2 a = ld8(e), c2 = ld8(e + 1);
            lf[0] = a.x; lf[1] = a.y; lf[2] = c2.x; lf[3] = c2.y;
        } else { lf[0] = lf[1] = lf[2] = lf[3] = 0.0f; }

        if (tx < 15) {
            #pragma unroll
            for (int r = 0; r < 4; ++r) rg[r] = rgS[r];
        } else if (tileX < 7) {
            gwait(&VFL[vOff + 4], gen);
            asm volatile("" ::: "memory");
            u64* e = VDL + (size_t)(vOff + 4) * 8 + tyq * 2;
            float2 a = ld8(e), c2 = ld8(e + 1);
            rg[0] = a.x; rg[1] = a.y; rg[2] = c2.x; rg[3] = c2.y;
        } else { rg[0] = rg[1] = rg[2] = rg[3] = 0.0f; }

        // ---- diffuse + block mean + adjust (all registers) ----
        float nv[4][4];
        float s = 0.0f;
        #pragma unroll
        for (int r = 0; r < 4; ++r) {
            #pragma unroll
            for (int c = 0; c < 4; ++c) {
                const float v = I[r][c];
                const float u = r       ? I[r - 1][c] : up[c];
                const float d = (r < 3) ? I[r + 1][c] : dn[c];
                const float l = c       ? I[r][c - 1] : lf[r];
                const float g = (c < 3) ? I[r][c + 1] : rg[r];
                const float t = cvaL[r + 1][c] * (d - v)
                              - cvaL[r][c]     * (v - u)
                              + chaL[r][c + 1] * (g - v)
                              - chaL[r][c]     * (v - l);
                const float nw = v + t;
                nv[r][c] = nw;
                s += nw;
            }
        }
        // 8x8 block = 2x2 thread group (lanes ^1 and ^16 — same wave, lockstep)
        s += __shfl_xor(s, 1);
        s += __shfl_xor(s, 16);
        const float mean  = s * (1.0f / 64.0f);
        const float ratio = useR ? (sv / (mean + EPSV)) : 1.0f;
        #pragma unroll
        for (int r = 0; r < 4; ++r)
            #pragma unroll
            for (int c = 0; c < 4; ++c) I[r][c] = nv[r][c] * ratio;
    }

    // ---- store final image ----
    #pragma unroll
    for (int r = 0; r < 4; ++r)
        *(float4*)(out_img + ((size_t)b * HH + y0 + r) * WW + x0) =
            make_float4(I[r][0], I[r][1], I[r][2], I[r][3]);
}

extern "C" void kernel_launch(void* const* d_in, const int* in_sizes, int n_in,
                              void* d_out, int out_size, void* d_ws, size_t ws_size,
                              hipStream_t stream) {
    const float* image  = (const float*)d_in[0];
    const float* source = (const float*)d_in[1];
    const float* mask   = (const float*)d_in[2];
    const float* ybic   = (const float*)d_in[3];
    const float* logk   = (const float*)d_in[4];

    float* out_img = (float*)d_out;                          // [B,1,H,W]
    float* out_cv  = out_img + (size_t)BB * HH * WW;         // [B,1,H-1,W]
    float* out_ch  = out_cv + (size_t)BB * (HH - 1) * WW;    // [B,1,H,W-1]

    int* flg = (int*)d_ws;                   // 5120 ints = 20KB of flags (reset each call)
    u64* dat = (u64*)((char*)d_ws + 32768);  // 512KB untagged edge data (flag-guarded)

    hipMemsetAsync(d_ws, 0, 20480, stream);

    int total = BB * HH * WW;
    prep_kernel<<<(total + 255) / 256, 256, 0, stream>>>(image, ybic, logk, out_cv, out_ch);

    dim3 grid(WW / 64, HH / 64, BB);
    persist_kernel<<<grid, 256, 0, stream>>>(ybic, out_img, out_cv, out_ch,
                                             source, mask, flg, dat);
}

// Round 7
// 220.500 us; speedup vs baseline: 2.1643x; 2.1643x over previous
//
#include <hip/hip_runtime.h>

#define HH 512
#define WW 512
#define BB 4
#define SH 64
#define SW 64
#define NPRE 128
#define LAMV 0.24f
#define EPSV 1e-8f

typedef unsigned long long u64;

// ---------------- prep: cv / ch edge weights (unchanged, verified) ----------------
__global__ __launch_bounds__(256) void prep_kernel(
    const float* __restrict__ image, const float* __restrict__ ybic,
    const float* __restrict__ logk,
    float* __restrict__ cv, float* __restrict__ ch)
{
    int idx = blockIdx.x * 256 + threadIdx.x;
    if (idx >= BB * HH * WW) return;
    int x = idx % WW;
    int y = (idx / WW) % HH;
    int b = idx / (WW * HH);

    float K = expf(logk[0]);
    float invK2 = 1.0f / (K * K);

    const float* img = image + (size_t)b * 3 * HH * WW;
    const float* yb  = ybic  + (size_t)b * HH * WW;

    float f0 = img[y * WW + x];
    float f1 = img[HH * WW + y * WW + x];
    float f2 = img[2 * HH * WW + y * WW + x];
    float f3 = yb[y * WW + x];

    if (y < HH - 1) {
        float s = fabsf(img[(y + 1) * WW + x] - f0)
                + fabsf(img[HH * WW + (y + 1) * WW + x] - f1)
                + fabsf(img[2 * HH * WW + (y + 1) * WW + x] - f2)
                + fabsf(yb[(y + 1) * WW + x] - f3);
        s *= 0.25f;
        cv[(size_t)b * (HH - 1) * WW + y * WW + x] = 1.0f / (1.0f + s * s * invK2);
    }
    if (x < WW - 1) {
        float s = fabsf(img[y * WW + x + 1] - f0)
                + fabsf(img[HH * WW + y * WW + x + 1] - f1)
                + fabsf(img[2 * HH * WW + y * WW + x + 1] - f2)
                + fabsf(yb[y * WW + x + 1] - f3);
        s *= 0.25f;
        ch[(size_t)b * HH * (WW - 1) + y * (WW - 1) + x] = 1.0f / (1.0f + s * s * invK2);
    }
}

// halo slot: [parity][edge][b][tileY][tileX][32 x u64]; edges 0=Top,1=Bot,2=Lft,3=Rgt
// Each u64 = {hiFloat, loFloat} with mantissa-LSB tags:
//   loFloat LSB = 1            (poison 0xAA.. has LSB 0 -> never matches)
//   hiFloat LSB = (gen>>1)&1   (alternates per reuse of a parity slot)
// 8B atomic store => tag+payload indivisible: ONE producer->consumer RT, no flags.
__device__ __forceinline__ u64* hslot(u64* halo, int p, int e, int b, int tY, int tX) {
    return halo + ((size_t)(((p * 4 + e) * BB + b) * 64 + tY * 8 + tX)) * 32;
}

__device__ __forceinline__ u64 pack2(float a, float b, unsigned phase) {
    unsigned ua = (__builtin_bit_cast(unsigned, a) & ~1u) | 1u;
    unsigned ub = (__builtin_bit_cast(unsigned, b) & ~1u) | phase;
    return ((u64)ub << 32) | ua;
}
__device__ __forceinline__ void st8(u64* p, u64 v) {
    __hip_atomic_store(p, v, __ATOMIC_RELAXED, __HIP_MEMORY_SCOPE_AGENT);
}
// poll one 16B edge (2 u64) until both tags match this generation
__device__ __forceinline__ void poll_edge(u64* e, unsigned phase, float out[4]) {
    u64 w0, w1;
    for (;;) {
        w0 = __hip_atomic_load(e + 0, __ATOMIC_RELAXED, __HIP_MEMORY_SCOPE_AGENT);
        w1 = __hip_atomic_load(e + 1, __ATOMIC_RELAXED, __HIP_MEMORY_SCOPE_AGENT);
        unsigned l0 = (unsigned)w0, h0 = (unsigned)(w0 >> 32);
        unsigned l1 = (unsigned)w1, h1 = (unsigned)(w1 >> 32);
        if (((l0 & 1u) == 1u) & ((h0 & 1u) == phase) &
            ((l1 & 1u) == 1u) & ((h1 & 1u) == phase)) {
            out[0] = __builtin_bit_cast(float, l0);
            out[1] = __builtin_bit_cast(float, h0);
            out[2] = __builtin_bit_cast(float, l1);
            out[3] = __builtin_bit_cast(float, h1);
            return;
        }
    }
}

// ---------------- persistent kernel: tagged-data single-RT handshakes ----------------
// Grid (8,8,4) x 256 thr; thread = 4x4 px; WG = 64x64 tile; all WGs resident by
// capacity (32KB LDS, 4 waves/WG). ONE __syncthreads per iteration (parity LDS).
__global__ __launch_bounds__(256) void persist_kernel(
    const float* __restrict__ ybic, float* __restrict__ out_img,
    const float* __restrict__ cv, const float* __restrict__ ch,
    const float* __restrict__ src, const float* __restrict__ mask,
    u64* __restrict__ halo)
{
    const int b = blockIdx.z, tileY = blockIdx.y, tileX = blockIdx.x;
    const int tid = threadIdx.x;
    const int tx = tid & 15, ty = tid >> 4;
    const int y0 = tileY * 64 + ty * 4, x0 = tileX * 64 + tx * 4;

    // ---- load state into registers (identical math to verified rounds) ----
    float I[4][4];
    #pragma unroll
    for (int r = 0; r < 4; ++r) {
        float4 t = *(const float4*)(ybic + ((size_t)b * HH + y0 + r) * WW + x0);
        I[r][0] = t.x; I[r][1] = t.y; I[r][2] = t.z; I[r][3] = t.w;
    }
    float cvaL[5][4];   // lambda * cv at interfaces y0-1 .. y0+3
    #pragma unroll
    for (int i = 0; i < 5; ++i) {
        int y = y0 - 1 + i;
        if (y >= 0 && y < HH - 1) {
            float4 t = *(const float4*)(cv + ((size_t)b * (HH - 1) + y) * WW + x0);
            cvaL[i][0] = t.x * LAMV; cvaL[i][1] = t.y * LAMV;
            cvaL[i][2] = t.z * LAMV; cvaL[i][3] = t.w * LAMV;
        } else {
            #pragma unroll
            for (int c = 0; c < 4; ++c) cvaL[i][c] = 0.0f;
        }
    }
    float chaL[4][5];   // lambda * ch at interfaces x0-1 .. x0+3
    #pragma unroll
    for (int r = 0; r < 4; ++r) {
        const float* row = ch + ((size_t)b * HH + y0 + r) * (WW - 1);
        #pragma unroll
        for (int j = 0; j < 5; ++j) {
            int x = x0 - 1 + j;
            chaL[r][j] = ((unsigned)x <= (unsigned)(WW - 2)) ? row[x] * LAMV : 0.0f;
        }
    }
    const size_t sidx = ((size_t)b * SH + (y0 >> 3)) * SW + (x0 >> 3);
    const float sv = src[sidx];
    const bool useR = (mask[sidx] >= 0.5f);

    // parity-double-buffered LDS edge exchange (intra-WG halo): 32 KB
    __shared__ float topE[2][16][16][4];
    __shared__ float botE[2][16][16][4];
    __shared__ float lftE[2][16][16][4];
    __shared__ float rgtE[2][16][16][4];

    const bool pubT = (ty == 0)  && (tileY > 0);
    const bool pubB = (ty == 15) && (tileY < 7);
    const bool pubL = (tx == 0)  && (tileX > 0);
    const bool pubR = (tx == 15) && (tileX < 7);

    #pragma unroll 1
    for (int k = 0; k < NPRE; ++k) {
        const int p = k & 1;
        const unsigned gen = (unsigned)(k + 1);
        const unsigned phase = (gen >> 1) & 1u;

        // ---- global publishes first (fire-and-forget; propagate under LDS work) ----
        if (pubT) {
            u64* e = hslot(halo, p, 0, b, tileY, tileX) + tx * 2;
            st8(e + 0, pack2(I[0][0], I[0][1], phase));
            st8(e + 1, pack2(I[0][2], I[0][3], phase));
        }
        if (pubB) {
            u64* e = hslot(halo, p, 1, b, tileY, tileX) + tx * 2;
            st8(e + 0, pack2(I[3][0], I[3][1], phase));
            st8(e + 1, pack2(I[3][2], I[3][3], phase));
        }
        if (pubL) {
            u64* e = hslot(halo, p, 2, b, tileY, tileX) + ty * 2;
            st8(e + 0, pack2(I[0][0], I[1][0], phase));
            st8(e + 1, pack2(I[2][0], I[3][0], phase));
        }
        if (pubR) {
            u64* e = hslot(halo, p, 3, b, tileY, tileX) + ty * 2;
            st8(e + 0, pack2(I[0][3], I[1][3], phase));
            st8(e + 1, pack2(I[2][3], I[3][3], phase));
        }

        // ---- LDS publish (intra-WG halo) ----
        #pragma unroll
        for (int c = 0; c < 4; ++c) {
            topE[p][ty][tx][c] = I[0][c];
            botE[p][ty][tx][c] = I[3][c];
            lftE[p][ty][tx][c] = I[c][0];
            rgtE[p][ty][tx][c] = I[c][3];
        }
        __syncthreads();   // single barrier: LDS buf[p] complete

        // ---- gather halos: LDS first (fast), then global polls (latest possible) ----
        float up[4], dn[4], lf[4], rg[4];
        if (ty > 0) {
            #pragma unroll
            for (int c = 0; c < 4; ++c) up[c] = botE[p][ty - 1][tx][c];
        }
        if (ty < 15) {
            #pragma unroll
            for (int c = 0; c < 4; ++c) dn[c] = topE[p][ty + 1][tx][c];
        }
        if (tx > 0) {
            #pragma unroll
            for (int r = 0; r < 4; ++r) lf[r] = rgtE[p][ty][tx - 1][r];
        }
        if (tx < 15) {
            #pragma unroll
            for (int r = 0; r < 4; ++r) rg[r] = lftE[p][ty][tx + 1][r];
        }

        if (ty == 0) {
            if (tileY > 0)
                poll_edge(hslot(halo, p, 1, b, tileY - 1, tileX) + tx * 2, phase, up);
            else { up[0] = up[1] = up[2] = up[3] = 0.0f; }
        }
        if (ty == 15) {
            if (tileY < 7)
                poll_edge(hslot(halo, p, 0, b, tileY + 1, tileX) + tx * 2, phase, dn);
            else { dn[0] = dn[1] = dn[2] = dn[3] = 0.0f; }
        }
        if (tx == 0) {
            if (tileX > 0)
                poll_edge(hslot(halo, p, 3, b, tileY, tileX - 1) + ty * 2, phase, lf);
            else { lf[0] = lf[1] = lf[2] = lf[3] = 0.0f; }
        }
        if (tx == 15) {
            if (tileX < 7)
                poll_edge(hslot(halo, p, 2, b, tileY, tileX + 1) + ty * 2, phase, rg);
            else { rg[0] = rg[1] = rg[2] = rg[3] = 0.0f; }
        }

        // ---- diffuse + block mean + adjust (all registers) ----
        float nv[4][4];
        float s = 0.0f;
        #pragma unroll
        for (int r = 0; r < 4; ++r) {
            #pragma unroll
            for (int c = 0; c < 4; ++c) {
                const float v = I[r][c];
                const float u = r       ? I[r - 1][c] : up[c];
                const float d = (r < 3) ? I[r + 1][c] : dn[c];
                const float l = c       ? I[r][c - 1] : lf[r];
                const float g = (c < 3) ? I[r][c + 1] : rg[r];
                const float t = cvaL[r + 1][c] * (d - v)
                              - cvaL[r][c]     * (v - u)
                              + chaL[r][c + 1] * (g - v)
                              - chaL[r][c]     * (v - l);
                const float w = v + t;
                nv[r][c] = w;
                s += w;
            }
        }
        // 8x8 block = 2x2 thread group (lanes ^1 and ^16, same wave)
        s += __shfl_xor(s, 1);
        s += __shfl_xor(s, 16);
        const float mean  = s * (1.0f / 64.0f);
        const float ratio = useR ? (sv / (mean + EPSV)) : 1.0f;
        #pragma unroll
        for (int r = 0; r < 4; ++r)
            #pragma unroll
            for (int c = 0; c < 4; ++c) I[r][c] = nv[r][c] * ratio;
    }

    // ---- store final image ----
    #pragma unroll
    for (int r = 0; r < 4; ++r)
        *(float4*)(out_img + ((size_t)b * HH + y0 + r) * WW + x0) =
            make_float4(I[r][0], I[r][1], I[r][2], I[r][3]);
}

extern "C" void kernel_launch(void* const* d_in, const int* in_sizes, int n_in,
                              void* d_out, int out_size, void* d_ws, size_t ws_size,
                              hipStream_t stream) {
    const float* image  = (const float*)d_in[0];
    const float* source = (const float*)d_in[1];
    const float* mask   = (const float*)d_in[2];
    const float* ybic   = (const float*)d_in[3];
    const float* logk   = (const float*)d_in[4];

    float* out_img = (float*)d_out;                          // [B,1,H,W]
    float* out_cv  = out_img + (size_t)BB * HH * WW;         // [B,1,H-1,W]
    float* out_ch  = out_cv + (size_t)BB * (HH - 1) * WW;    // [B,1,H,W-1]

    u64* halo = (u64*)d_ws;   // 512 KB tagged edge slots; NO reset needed:
                              // poison LSB=0 never matches, phase bit kills stale gens

    int total = BB * HH * WW;
    prep_kernel<<<(total + 255) / 256, 256, 0, stream>>>(image, ybic, logk, out_cv, out_ch);

    dim3 grid(WW / 64, HH / 64, BB);
    persist_kernel<<<grid, 256, 0, stream>>>(ybic, out_img, out_cv, out_ch,
                                             source, mask, halo);
}

// Round 8
// 203.480 us; speedup vs baseline: 2.3454x; 1.0836x over previous
//
#include <hip/hip_runtime.h>

#define HH 512
#define WW 512
#define BB 4
#define SH 64
#define SW 64
#define NPRE 128
#define LAMV 0.24f
#define EPSV 1e-8f

typedef unsigned long long u64;

// ---------------- prep: cv / ch edge weights (unchanged, verified) ----------------
__global__ __launch_bounds__(256) void prep_kernel(
    const float* __restrict__ image, const float* __restrict__ ybic,
    const float* __restrict__ logk,
    float* __restrict__ cv, float* __restrict__ ch)
{
    int idx = blockIdx.x * 256 + threadIdx.x;
    if (idx >= BB * HH * WW) return;
    int x = idx % WW;
    int y = (idx / WW) % HH;
    int b = idx / (WW * HH);

    float K = expf(logk[0]);
    float invK2 = 1.0f / (K * K);

    const float* img = image + (size_t)b * 3 * HH * WW;
    const float* yb  = ybic  + (size_t)b * HH * WW;

    float f0 = img[y * WW + x];
    float f1 = img[HH * WW + y * WW + x];
    float f2 = img[2 * HH * WW + y * WW + x];
    float f3 = yb[y * WW + x];

    if (y < HH - 1) {
        float s = fabsf(img[(y + 1) * WW + x] - f0)
                + fabsf(img[HH * WW + (y + 1) * WW + x] - f1)
                + fabsf(img[2 * HH * WW + (y + 1) * WW + x] - f2)
                + fabsf(yb[(y + 1) * WW + x] - f3);
        s *= 0.25f;
        cv[(size_t)b * (HH - 1) * WW + y * WW + x] = 1.0f / (1.0f + s * s * invK2);
    }
    if (x < WW - 1) {
        float s = fabsf(img[y * WW + x + 1] - f0)
                + fabsf(img[HH * WW + y * WW + x + 1] - f1)
                + fabsf(img[2 * HH * WW + y * WW + x + 1] - f2)
                + fabsf(yb[y * WW + x + 1] - f3);
        s *= 0.25f;
        ch[(size_t)b * HH * (WW - 1) + y * (WW - 1) + x] = 1.0f / (1.0f + s * s * invK2);
    }
}

// halo slot: [parity][edge][b][tileY][tileX][32 x u64]; edges 0=Top,1=Bot,2=Lft,3=Rgt
// Each u64 = {hiFloat, loFloat} with mantissa-LSB tags:
//   loFloat LSB = 1            (poison 0xAA.. has LSB 0 -> never matches)
//   hiFloat LSB = (gen>>1)&1   (alternates per reuse of a parity slot)
// 8B atomic store => tag+payload indivisible: ONE producer->consumer RT, no flags.
#define PSTRIDE (4 * BB * 64 * 32)   // u64 elements between parity 0 and 1

__device__ __forceinline__ u64* hslot0(u64* halo, int e, int b, int tY, int tX) {
    return halo + ((size_t)((e * BB + b) * 64 + tY * 8 + tX)) * 32;
}

__device__ __forceinline__ u64 pack2(float a, float b, unsigned phase) {
    unsigned ua = (__builtin_bit_cast(unsigned, a) & ~1u) | 1u;
    unsigned ub = (__builtin_bit_cast(unsigned, b) & ~1u) | phase;
    return ((u64)ub << 32) | ua;
}
__device__ __forceinline__ void st8(u64* p, u64 v) {
    __hip_atomic_store(p, v, __ATOMIC_RELAXED, __HIP_MEMORY_SCOPE_AGENT);
}
__device__ __forceinline__ u64 ld8(u64* p) {
    return __hip_atomic_load(p, __ATOMIC_RELAXED, __HIP_MEMORY_SCOPE_AGENT);
}
// check tags of one 16B edge; unpack on success
__device__ __forceinline__ bool chk2(u64 w0, u64 w1, unsigned phase, float out[4]) {
    unsigned l0 = (unsigned)w0, h0 = (unsigned)(w0 >> 32);
    unsigned l1 = (unsigned)w1, h1 = (unsigned)(w1 >> 32);
    if (((l0 & 1u) == 1u) & ((h0 & 1u) == phase) &
        ((l1 & 1u) == 1u) & ((h1 & 1u) == phase)) {
        out[0] = __builtin_bit_cast(float, l0);
        out[1] = __builtin_bit_cast(float, h0);
        out[2] = __builtin_bit_cast(float, l1);
        out[3] = __builtin_bit_cast(float, h1);
        return true;
    }
    return false;
}

// ---------------- persistent kernel: fused concurrent single-RT handshakes ----------------
// Grid (8,8,4) x 256 thr; thread = 4x4 px; WG = 64x64 tile. ONE __syncthreads per
// iteration (parity LDS); one fused spin loop with 8 back-to-back edge loads so all
// outstanding direction RTs overlap (round-7 lesson: divergent per-direction spin
// loops serialize up to 3 IF$ RTs within a wave).
__global__ __launch_bounds__(256) void persist_kernel(
    const float* __restrict__ ybic, float* __restrict__ out_img,
    const float* __restrict__ cv, const float* __restrict__ ch,
    const float* __restrict__ src, const float* __restrict__ mask,
    u64* __restrict__ halo)
{
    const int b = blockIdx.z, tileY = blockIdx.y, tileX = blockIdx.x;
    const int tid = threadIdx.x;
    const int tx = tid & 15, ty = tid >> 4;
    const int y0 = tileY * 64 + ty * 4, x0 = tileX * 64 + tx * 4;

    // ---- load state into registers (identical math to verified rounds) ----
    float I[4][4];
    #pragma unroll
    for (int r = 0; r < 4; ++r) {
        float4 t = *(const float4*)(ybic + ((size_t)b * HH + y0 + r) * WW + x0);
        I[r][0] = t.x; I[r][1] = t.y; I[r][2] = t.z; I[r][3] = t.w;
    }
    float cvaL[5][4];   // lambda * cv at interfaces y0-1 .. y0+3
    #pragma unroll
    for (int i = 0; i < 5; ++i) {
        int y = y0 - 1 + i;
        if (y >= 0 && y < HH - 1) {
            float4 t = *(const float4*)(cv + ((size_t)b * (HH - 1) + y) * WW + x0);
            cvaL[i][0] = t.x * LAMV; cvaL[i][1] = t.y * LAMV;
            cvaL[i][2] = t.z * LAMV; cvaL[i][3] = t.w * LAMV;
        } else {
            #pragma unroll
            for (int c = 0; c < 4; ++c) cvaL[i][c] = 0.0f;
        }
    }
    float chaL[4][5];   // lambda * ch at interfaces x0-1 .. x0+3
    #pragma unroll
    for (int r = 0; r < 4; ++r) {
        const float* row = ch + ((size_t)b * HH + y0 + r) * (WW - 1);
        #pragma unroll
        for (int j = 0; j < 5; ++j) {
            int x = x0 - 1 + j;
            chaL[r][j] = ((unsigned)x <= (unsigned)(WW - 2)) ? row[x] * LAMV : 0.0f;
        }
    }
    const size_t sidx = ((size_t)b * SH + (y0 >> 3)) * SW + (x0 >> 3);
    const float sv = src[sidx];
    const bool useR = (mask[sidx] >= 0.5f);

    // parity-double-buffered LDS edge exchange (intra-WG halo): 32 KB
    __shared__ float topE[2][16][16][4];
    __shared__ float botE[2][16][16][4];
    __shared__ float lftE[2][16][16][4];
    __shared__ float rgtE[2][16][16][4];

    // publish roles (round-7, verified)
    const bool pubT = (ty == 0)  && (tileY > 0);
    const bool pubB = (ty == 15) && (tileY < 7);
    const bool pubL = (tx == 0)  && (tileX > 0);
    const bool pubR = (tx == 15) && (tileX < 7);
    // poll roles
    const bool pollU = (ty == 0)  && (tileY > 0);
    const bool pollD = (ty == 15) && (tileY < 7);
    const bool pollL = (tx == 0)  && (tileX > 0);
    const bool pollR = (tx == 15) && (tileX < 7);

    // precomputed parity-0 pointers (parity adds PSTRIDE); dummy = own top slot
    u64* dummy = hslot0(halo, 0, b, tileY, tileX) + tx * 2;
    u64* pTb = dummy;                                          // own top edge
    u64* pBb = hslot0(halo, 1, b, tileY, tileX) + tx * 2;
    u64* pLb = hslot0(halo, 2, b, tileY, tileX) + ty * 2;
    u64* pRb = hslot0(halo, 3, b, tileY, tileX) + ty * 2;
    u64* euB = pollU ? hslot0(halo, 1, b, tileY - 1, tileX) + tx * 2 : dummy;
    u64* edB = pollD ? hslot0(halo, 0, b, tileY + 1, tileX) + tx * 2 : dummy;
    u64* elB = pollR ? dummy : (pollL ? hslot0(halo, 3, b, tileY, tileX - 1) + ty * 2 : dummy);
    u64* erB = pollR ? hslot0(halo, 2, b, tileY, tileX + 1) + ty * 2 : dummy;
    if (pollL) elB = hslot0(halo, 3, b, tileY, tileX - 1) + ty * 2;

    // halo values; zeros persist for image-boundary lanes (never overwritten)
    float up[4] = {0, 0, 0, 0}, dn[4] = {0, 0, 0, 0};
    float lf[4] = {0, 0, 0, 0}, rg[4] = {0, 0, 0, 0};

    #pragma unroll 1
    for (int k = 0; k < NPRE; ++k) {
        const int p = k & 1;
        const unsigned gen = (unsigned)(k + 1);
        const unsigned phase = (gen >> 1) & 1u;
        const size_t po = (size_t)p * PSTRIDE;

        // ---- global publishes first (fire-and-forget; propagate under LDS work) ----
        if (pubT) {
            u64* e = pTb + po;
            st8(e + 0, pack2(I[0][0], I[0][1], phase));
            st8(e + 1, pack2(I[0][2], I[0][3], phase));
        }
        if (pubB) {
            u64* e = pBb + po;
            st8(e + 0, pack2(I[3][0], I[3][1], phase));
            st8(e + 1, pack2(I[3][2], I[3][3], phase));
        }
        if (pubL) {
            u64* e = pLb + po;
            st8(e + 0, pack2(I[0][0], I[1][0], phase));
            st8(e + 1, pack2(I[2][0], I[3][0], phase));
        }
        if (pubR) {
            u64* e = pRb + po;
            st8(e + 0, pack2(I[0][3], I[1][3], phase));
            st8(e + 1, pack2(I[2][3], I[3][3], phase));
        }

        // ---- LDS publish (intra-WG halo) ----
        #pragma unroll
        for (int c = 0; c < 4; ++c) {
            topE[p][ty][tx][c] = I[0][c];
            botE[p][ty][tx][c] = I[3][c];
            lftE[p][ty][tx][c] = I[c][0];
            rgtE[p][ty][tx][c] = I[c][3];
        }
        __syncthreads();   // single barrier: LDS buf[p] complete

        // ---- gather intra-WG halos from LDS ----
        if (ty > 0) {
            #pragma unroll
            for (int c = 0; c < 4; ++c) up[c] = botE[p][ty - 1][tx][c];
        }
        if (ty < 15) {
            #pragma unroll
            for (int c = 0; c < 4; ++c) dn[c] = topE[p][ty + 1][tx][c];
        }
        if (tx > 0) {
            #pragma unroll
            for (int r = 0; r < 4; ++r) lf[r] = rgtE[p][ty][tx - 1][r];
        }
        if (tx < 15) {
            #pragma unroll
            for (int r = 0; r < 4; ++r) rg[r] = lftE[p][ty][tx + 1][r];
        }

        // ---- fused concurrent poll: 8 loads issued back-to-back, all RTs overlap ----
        {
            u64* eu = euB + po; u64* ed = edB + po;
            u64* el = elB + po; u64* er = erB + po;
            bool du = !pollU, dd = !pollD, dl = !pollL, dr = !pollR;
            while (!(du & dd & dl & dr)) {
                u64 a0 = ld8(eu + 0), a1 = ld8(eu + 1);
                u64 b0 = ld8(ed + 0), b1 = ld8(ed + 1);
                u64 c0 = ld8(el + 0), c1 = ld8(el + 1);
                u64 d0 = ld8(er + 0), d1 = ld8(er + 1);
                if (!du && chk2(a0, a1, phase, up)) du = true;
                if (!dd && chk2(b0, b1, phase, dn)) dd = true;
                if (!dl && chk2(c0, c1, phase, lf)) dl = true;
                if (!dr && chk2(d0, d1, phase, rg)) dr = true;
            }
        }

        // ---- diffuse + block mean + adjust (all registers) ----
        float nv[4][4];
        float s = 0.0f;
        #pragma unroll
        for (int r = 0; r < 4; ++r) {
            #pragma unroll
            for (int c = 0; c < 4; ++c) {
                const float v = I[r][c];
                const float u = r       ? I[r - 1][c] : up[c];
                const float d = (r < 3) ? I[r + 1][c] : dn[c];
                const float l = c       ? I[r][c - 1] : lf[r];
                const float g = (c < 3) ? I[r][c + 1] : rg[r];
                const float t = cvaL[r + 1][c] * (d - v)
                              - cvaL[r][c]     * (v - u)
                              + chaL[r][c + 1] * (g - v)
                              - chaL[r][c]     * (v - l);
                const float w = v + t;
                nv[r][c] = w;
                s += w;
            }
        }
        // 8x8 block = 2x2 thread group (lanes ^1 and ^16, same wave)
        s += __shfl_xor(s, 1);
        s += __shfl_xor(s, 16);
        const float mean  = s * (1.0f / 64.0f);
        const float ratio = useR ? (sv / (mean + EPSV)) : 1.0f;
        #pragma unroll
        for (int r = 0; r < 4; ++r)
            #pragma unroll
            for (int c = 0; c < 4; ++c) I[r][c] = nv[r][c] * ratio;
    }

    // ---- store final image ----
    #pragma unroll
    for (int r = 0; r < 4; ++r)
        *(float4*)(out_img + ((size_t)b * HH + y0 + r) * WW + x0) =
            make_float4(I[r][0], I[r][1], I[r][2], I[r][3]);
}

extern "C" void kernel_launch(void* const* d_in, const int* in_sizes, int n_in,
                              void* d_out, int out_size, void* d_ws, size_t ws_size,
                              hipStream_t stream) {
    const float* image  = (const float*)d_in[0];
    const float* source = (const float*)d_in[1];
    const float* mask   = (const float*)d_in[2];
    const float* ybic   = (const float*)d_in[3];
    const float* logk   = (const float*)d_in[4];

    float* out_img = (float*)d_out;                          // [B,1,H,W]
    float* out_cv  = out_img + (size_t)BB * HH * WW;         // [B,1,H-1,W]
    float* out_ch  = out_cv + (size_t)BB * (HH - 1) * WW;    // [B,1,H,W-1]

    u64* halo = (u64*)d_ws;   // 512 KB tagged edge slots; NO reset needed:
                              // poison LSB=0 never matches, phase bit kills stale gens

    int total = BB * HH * WW;
    prep_kernel<<<(total + 255) / 256, 256, 0, stream>>>(image, ybic, logk, out_cv, out_ch);

    dim3 grid(WW / 64, HH / 64, BB);
    persist_kernel<<<grid, 256, 0, stream>>>(ybic, out_img, out_cv, out_ch,
                                             source, mask, halo);
}